// Round 7
// baseline (310.003 us; speedup 1.0000x reference)
//
#include <hip/hip_runtime.h>

#define NB   4
#define C_IN 256
#define CQD  64
#define NPT  4096
#define L2E  1.44269504088896f

typedef __attribute__((ext_vector_type(8)))  short bf16x8;
typedef __attribute__((ext_vector_type(4)))  float f32x4;
typedef __attribute__((ext_vector_type(16))) float f32x16;
typedef unsigned short u16;
typedef unsigned int   u32;

#define EXP2F(x)        __builtin_amdgcn_exp2f(x)
#define MFMA32(A,B,C)   __builtin_amdgcn_mfma_f32_16x16x32_bf16(A,B,C,0,0,0)
#define MFMA3216(A,B,C) __builtin_amdgcn_mfma_f32_32x32x16_bf16(A,B,C,0,0,0)

__device__ __forceinline__ u16 f2bf(float f) {          // RNE (cold paths)
    u32 u = __float_as_uint(f);
    u += 0x7fff + ((u >> 16) & 1);
    return (u16)(u >> 16);
}
// one v_perm: (bf16_trunc(hi)<<16) | bf16_trunc(lo)
__device__ __forceinline__ u32 pack_trunc(float lo, float hi) {
    return __builtin_amdgcn_perm(__float_as_uint(hi), __float_as_uint(lo), 0x07060302u);
}

// ---------------------------------------------------------------------------
// prep: pack wq|wk|wv into bf16 wbf[384][256], biases into bias[384]
// ---------------------------------------------------------------------------
__global__ void prep_kernel(
    const float* __restrict__ wq, const float* __restrict__ bq,
    const float* __restrict__ wk, const float* __restrict__ bk,
    const float* __restrict__ wv, const float* __restrict__ bv,
    u16* __restrict__ wbf, float* __restrict__ bias)
{
    const int gid = blockIdx.x*256 + threadIdx.x;
    if (gid < 384*256) {
        const int r = gid >> 8, c = gid & 255;
        const float v = (r < 64) ? wq[r*256 + c]
                      : (r < 128) ? wk[(r-64)*256 + c]
                                  : wv[(r-128)*256 + c];
        wbf[gid] = f2bf(v);
    } else if (gid < 384*256 + 384) {
        const int r = gid - 384*256;
        bias[r] = (r < 64) ? bq[r] : (r < 128) ? bk[r-64] : bv[r-128];
    }
}

// ---------------------------------------------------------------------------
// proj: MFMA pointwise projections, x read ONCE. Wave w owns tiles T=4*ot+w.
// grid (N/32, B), block 256.
// ---------------------------------------------------------------------------
union ProjShared {
    u16 x_t[32][264];                            // [n][c] bf16, stride 528B
    struct { u16 qk[32][136]; u16 vl[256][40]; } ep;
};

__global__ __launch_bounds__(256) void proj_kernel(
    const float* __restrict__ x, const u16* __restrict__ wbf,
    const float* __restrict__ bias,
    u16* __restrict__ qT, u16* __restrict__ kT, u16* __restrict__ vbf)
{
    __shared__ ProjShared sh;

    const int t  = threadIdx.x;
    const int n0 = blockIdx.x * 32;
    const int b  = blockIdx.y;

    {   // stage x tile transposed -> bf16 LDS
        const int ln = t & 31;
        const int cg = t >> 5;
        #pragma unroll
        for (int rr = 0; rr < 8; rr++) {
            const int c = 4*cg + 32*rr;
            const float f0 = x[((size_t)(b*C_IN + c+0))*NPT + n0 + ln];
            const float f1 = x[((size_t)(b*C_IN + c+1))*NPT + n0 + ln];
            const float f2 = x[((size_t)(b*C_IN + c+2))*NPT + n0 + ln];
            const float f3 = x[((size_t)(b*C_IN + c+3))*NPT + n0 + ln];
            ushort4 u4;
            u4.x = f2bf(f0); u4.y = f2bf(f1); u4.z = f2bf(f2); u4.w = f2bf(f3);
            *(ushort4*)&sh.x_t[ln][c] = u4;
        }
    }
    __syncthreads();

    const int w = t >> 6, l = t & 63, q = l >> 4, c16 = l & 15;

    f32x4 acc[6][2];
    #pragma unroll
    for (int ot = 0; ot < 6; ot++)
        #pragma unroll
        for (int nt = 0; nt < 2; nt++)
            acc[ot][nt] = (f32x4){0.f, 0.f, 0.f, 0.f};

    #pragma unroll
    for (int kk = 0; kk < 8; kk++) {
        const bf16x8 bf0 = *(const bf16x8*)&sh.x_t[c16     ][kk*32 + 8*q];
        const bf16x8 bf1 = *(const bf16x8*)&sh.x_t[16 + c16][kk*32 + 8*q];
        #pragma unroll
        for (int ot = 0; ot < 6; ot++) {
            const int o = 16*(4*ot + w) + c16;
            const bf16x8 af = *(const bf16x8*)&wbf[(size_t)o*C_IN + kk*32 + 8*q];
            acc[ot][0] = MFMA32(af, bf0, acc[ot][0]);
            acc[ot][1] = MFMA32(af, bf1, acc[ot][1]);
        }
    }
    __syncthreads();   // x_t dead; reuse LDS for epilogue staging

    #pragma unroll
    for (int ot = 0; ot < 6; ot++) {
        const int T  = 4*ot + w;
        const int ob = 16*T + 4*q;
        float b0 = bias[ob+0], b1 = bias[ob+1], b2 = bias[ob+2], b3 = bias[ob+3];
        #pragma unroll
        for (int nt = 0; nt < 2; nt++) {
            const f32x4 a = acc[ot][nt];
            const float v0 = a[0]+b0, v1 = a[1]+b1, v2 = a[2]+b2, v3 = a[3]+b3;
            if (ot < 2) {
                uint2 u;
                u.x = (u32)f2bf(v0) | ((u32)f2bf(v1) << 16);
                u.y = (u32)f2bf(v2) | ((u32)f2bf(v3) << 16);
                *(uint2*)&sh.ep.qk[16*nt + c16][16*T + 4*q] = u;
            } else {
                const int cb = 16*T - 128 + 4*q;
                sh.ep.vl[cb+0][16*nt + c16] = f2bf(v0);
                sh.ep.vl[cb+1][16*nt + c16] = f2bf(v1);
                sh.ep.vl[cb+2][16*nt + c16] = f2bf(v2);
                sh.ep.vl[cb+3][16*nt + c16] = f2bf(v3);
            }
        }
    }
    __syncthreads();

    {   // coalesced global stores
        const int n  = t >> 3;
        const int o8 = (t & 7) * 8;
        *(uint4*)&qT[((size_t)b*NPT + n0 + n)*CQD + o8] = *(uint4*)&sh.ep.qk[n][o8];
        *(uint4*)&kT[((size_t)b*NPT + n0 + n)*CQD + o8] = *(uint4*)&sh.ep.qk[n][64 + o8];
        u16* vrow = &vbf[((size_t)b*C_IN + t)*NPT + n0];
        #pragma unroll
        for (int j = 0; j < 4; j++)
            *(uint4*)&vrow[8*j] = *(uint4*)&sh.ep.vl[t][8*j];
    }
}

// ---------------------------------------------------------------------------
// stats: no-max partial softmax sums over 1024-wide m-split via MFMA.
// grid (4 msplit, N/64, B), block 256.
// ---------------------------------------------------------------------------
__global__ __launch_bounds__(256) void stats_kernel(
    const u16* __restrict__ qT, const u16* __restrict__ kT,
    float* __restrict__ psum)
{
    const int t = threadIdx.x;
    const int w = t >> 6, l = t & 63, q = l >> 4, c16 = l & 15;
    const int ms = blockIdx.x, nt = blockIdx.y, b = blockIdx.z;
    const int nb = nt*64 + 16*w;

    const bf16x8* qp = (const bf16x8*)&qT[((size_t)b*NPT + nb + c16)*CQD + 8*q];
    const bf16x8 aq0 = qp[0];
    const bf16x8 aq1 = qp[4];

    float rz[4] = {0.f, 0.f, 0.f, 0.f};

    for (int m0 = ms*1024; m0 < ms*1024 + 1024; m0 += 64) {
        f32x4 s[4];
        #pragma unroll
        for (int mj = 0; mj < 4; mj++) {
            const bf16x8* kp = (const bf16x8*)&kT[((size_t)b*NPT + m0 + 16*mj + c16)*CQD + 8*q];
            f32x4 a = {0.f, 0.f, 0.f, 0.f};
            a = MFMA32(aq0, kp[0], a);
            a = MFMA32(aq1, kp[4], a);
            s[mj] = a;
        }
        #pragma unroll
        for (int r = 0; r < 4; r++) {
            rz[r] += EXP2F(s[0][r]*L2E) + EXP2F(s[1][r]*L2E)
                   + EXP2F(s[2][r]*L2E) + EXP2F(s[3][r]*L2E);
        }
    }
    #pragma unroll
    for (int r = 0; r < 4; r++) {
        float Z = rz[r];
        #pragma unroll
        for (int d = 1; d < 16; d <<= 1) Z += __shfl_xor(Z, d, 64);
        if (c16 == 0)
            psum[((size_t)(b*4 + ms))*NPT + nb + 4*q + r] = Z;
    }
}

// ---------------------------------------------------------------------------
// merge: Lrow[n] = log2(sum of 4 partial Z)
// ---------------------------------------------------------------------------
__global__ void merge_kernel(const float* __restrict__ psum, float* __restrict__ Lrow)
{
    const int g = blockIdx.x*256 + threadIdx.x;
    const int b = g >> 12;
    const int n = g & 4095;
    float Z = 0.f;
    #pragma unroll
    for (int s = 0; s < 4; s++) Z += psum[((size_t)(b*4+s))*NPT + n];
    Lrow[(size_t)b*NPT + n] = __log2f(Z);
}

// ---------------------------------------------------------------------------
// attn: block = 64 m x 128 c (cs in {0,1}), full n sweep. s via 16x16x32
// (p-write-friendly C/D), PV via 32x32x16 (half the LDS bytes per FLOP).
// Each wave: s for its 16-n' stripe; PV for (m-half w0, c-rows 64*w1..+63)
// as two 32x32 o-tiles SHARING p B-fragments. Flat-unit p layout: unit
// idx17 = wv*16+qv*4+mj (uint2 = 4 consecutive n' at one m), U = idx17*17+c16.
// Writes 4-way banked, reads conflict-free. One barrier/iter, double-buffered.
// grid 512 flat (id&7 = (b,cs) -> XCD-pinned slabs), block 256.
// ---------------------------------------------------------------------------
__global__ __launch_bounds__(256, 2) void attn_kernel(
    const u16* __restrict__ qT, const u16* __restrict__ kT, const u16* __restrict__ vbf,
    const float* __restrict__ Lrow, const float* __restrict__ gamma,
    const float* __restrict__ x, float* __restrict__ out)
{
    __shared__ uint2 p_l[2][1088];   // 2 x 8704 B

    const int t = threadIdx.x;
    const int w = t >> 6, l = t & 63, q = l >> 4, c16 = l & 15;
    const int w0 = w & 1, w1 = w >> 1;       // m-half / c-half (PV roles)
    const int l5 = l >> 5, lm = l & 31;      // 32-lane group / lane-in-32

    const int id = blockIdx.x;               // 0..511
    const int b  = (id & 7) >> 1, cs = id & 1;
    const int mt = id >> 3;
    const int m0 = mt * 64;

    // k B-fragments (s stage) in registers for the whole n sweep
    bf16x8 kf[4][2];
    #pragma unroll
    for (int mj = 0; mj < 4; mj++) {
        const bf16x8* kp = (const bf16x8*)&kT[((size_t)b*NPT + m0 + 16*mj + c16)*CQD + 8*q];
        kf[mj][0] = kp[0];
        kf[mj][1] = kp[4];
    }

    f32x16 acc[2];   // two 32c x 32m o-tiles: c = cs*128+64*w1+32*cq+..., m = m0+32*w0+lm
    #pragma unroll
    for (int cq = 0; cq < 2; cq++)
        #pragma unroll
        for (int r = 0; r < 16; r++) acc[cq][r] = 0.f;

    const u16*  qrow = &qT[((size_t)b*NPT + 16*w + c16)*CQD + 8*q];
    const float* Lb  = &Lrow[(size_t)b*NPT + 16*w + 4*q];
    const u16*  vb   = &vbf[((size_t)(b*C_IN + cs*128 + 64*w1 + lm))*NPT + 8*l5];

    // LDS unit indices
    const int Uw  = (w*16 + q*4)*17 + c16;                 // writes: + mj*17
    const int mj2 = 2*w0 + (q & 1);                        // read m-col group
    const int Ur  = (8*l5 + mj2)*17 + c16;                 // reads: + st*16*17

    bf16x8 qa0 = *(const bf16x8*)qrow;
    bf16x8 qa1 = *(const bf16x8*)(qrow + 32);

    int buf = 0;
    for (int nt = 0; nt < 64; nt++) {
        const int n0 = nt * 64;

        // s: wave's 16 n' rows x 64 m  (16x16x32)
        f32x4 s[4];
        #pragma unroll
        for (int mj = 0; mj < 4; mj++) {
            f32x4 a = {0.f, 0.f, 0.f, 0.f};
            a = MFMA32(qa0, kf[mj][0], a);
            a = MFMA32(qa1, kf[mj][1], a);
            s[mj] = a;
        }
        if (nt < 63) {   // prefetch next q fragment
            qa0 = *(const bf16x8*)(qrow + (size_t)(n0 + 64)*CQD);
            qa1 = *(const bf16x8*)(qrow + (size_t)(n0 + 64)*CQD + 32);
        }
        // v A-fragments (32x32x16 A: row c = lane&31, k = 8*l5 + e)
        bf16x8 va[2][4];
        #pragma unroll
        for (int cq = 0; cq < 2; cq++)
            #pragma unroll
            for (int st = 0; st < 4; st++)
                va[cq][st] = *(const bf16x8*)(vb + (size_t)(32*cq)*NPT + n0 + 16*st);

        const float4 Lr = *(const float4*)(Lb + n0);

        // p = exp2(s*L2E - Lrow), trunc-pack, store flat units
        #pragma unroll
        for (int mj = 0; mj < 4; mj++) {
            const float p0 = EXP2F(s[mj][0]*L2E - Lr.x);
            const float p1 = EXP2F(s[mj][1]*L2E - Lr.y);
            const float p2 = EXP2F(s[mj][2]*L2E - Lr.z);
            const float p3 = EXP2F(s[mj][3]*L2E - Lr.w);
            uint2 u;
            u.x = pack_trunc(p0, p1);
            u.y = pack_trunc(p2, p3);
            p_l[buf][Uw + mj*17] = u;
        }
        __syncthreads();

        // PV: 4 k-steps of 32x32x16; p B-frag shared by both c-quadrants
        #pragma unroll
        for (int st = 0; st < 4; st++) {
            const int U0 = Ur + st*272;          // st*16*17
            const uint2 e0 = p_l[buf][U0];
            const uint2 e1 = p_l[buf][U0 + 68];  // qv+1
            uint4 bfu = make_uint4(e0.x, e0.y, e1.x, e1.y);
            const bf16x8 pf = *(bf16x8*)&bfu;
            acc[0] = MFMA3216(va[0][st], pf, acc[0]);
            acc[1] = MFMA3216(va[1][st], pf, acc[1]);
        }
        buf ^= 1;
    }

    // epilogue: C/D 32x32 layout col = lane&31, row = (r&3)+8*(r>>2)+4*l5
    const float g = gamma[0];
    #pragma unroll
    for (int cq = 0; cq < 2; cq++) {
        const int cb = cs*128 + 64*w1 + 32*cq + 4*l5;
        #pragma unroll
        for (int r = 0; r < 16; r++) {
            const int c = cb + (r & 3) + 8*(r >> 2);
            const size_t o = ((size_t)(b*C_IN + c))*NPT + m0 + 32*w0 + lm;
            out[o] = g*acc[cq][r] + x[o];
        }
    }
}

// ---------------------------------------------------------------------------
extern "C" void kernel_launch(void* const* d_in, const int* in_sizes, int n_in,
                              void* d_out, int out_size, void* d_ws, size_t ws_size,
                              hipStream_t stream)
{
    const float* x     = (const float*)d_in[0];
    const float* wq    = (const float*)d_in[1];
    const float* bq    = (const float*)d_in[2];
    const float* wk    = (const float*)d_in[3];
    const float* bk    = (const float*)d_in[4];
    const float* wv    = (const float*)d_in[5];
    const float* bv    = (const float*)d_in[6];
    const float* gamma = (const float*)d_in[7];
    float* out = (float*)d_out;

    u16* qT  = (u16*)d_ws;                              // 2 MB
    u16* kT  = qT  + (size_t)NB*NPT*CQD;                // 2 MB
    u16* vbf = kT  + (size_t)NB*NPT*CQD;                // 8 MB
    u16* wbf = vbf + (size_t)NB*C_IN*NPT;               // 192 KB
    float* fp    = (float*)(wbf + 384*256);
    float* bias  = fp;                                  // 384
    float* psum  = bias + 384;                          // 64 KB
    float* Lrow  = psum + (size_t)NB*4*NPT;             // 64 KB

    prep_kernel<<<dim3(386), 256, 0, stream>>>(wq, bq, wk, bk, wv, bv, wbf, bias);
    proj_kernel<<<dim3(NPT/32, NB), 256, 0, stream>>>(x, wbf, bias, qT, kT, vbf);
    stats_kernel<<<dim3(4, NPT/64, NB), 256, 0, stream>>>(qT, kT, psum);
    merge_kernel<<<dim3(64), 256, 0, stream>>>(psum, Lrow);
    attn_kernel<<<dim3(512), 256, 0, stream>>>(qT, kT, vbf, Lrow, gamma, x, out);
}